// Round 7
// baseline (1848.709 us; speedup 1.0000x reference)
//
#include <hip/hip_runtime.h>

typedef _Float16 h8 __attribute__((ext_vector_type(8)));
typedef _Float16 h4 __attribute__((ext_vector_type(4)));
typedef float f4 __attribute__((ext_vector_type(4)));

#define SEQ_LEN 50
#define HID 64
#define HS 72      // halves per h row: 144B pitch; 16B-aligned b128 reads
#define NSEQ 32    // sequences per block (2 n-tiles per wave)

#if __has_builtin(__builtin_amdgcn_exp2f)
#define EXP2(x) __builtin_amdgcn_exp2f(x)
#else
extern "C" __device__ float __ocml_native_exp2_f32(float);
#define EXP2(x) __ocml_native_exp2_f32(x)
#endif
#define RCP(x) __builtin_amdgcn_rcpf(x)

#define LOG2E  1.442695041f
#define LOG2E2 2.885390082f

// TRANSPOSED orientation: gates^T = W_ext @ [h; x; 1].
// Block = 128 threads = 2 waves, NSEQ=32 sequences (2 n-tiles per wave).
// Wave w owns units 32w..32w+31 for ALL 32 seqs. Aw/Ax register fragments are
// shared across n-tiles, so doubling n amortizes the ~600 cyc/wave-step fixed
// overhead (addressing, bx build, barrier, loop) over 2x MFMA+activation work
// (R6 counters: busy 1072 cyc/step, activations only ~460 -> overhead bound).
// D layout: col=lane&15 = seq, row=quad*4+r = unit -> lane's 4 outputs are
// consecutive units of one seq -> single ds_write_b64 per (d, n-tile).
// x-projection folded into MFMA with C=0 (A_x nonzero only in quad 0).
//
// Activations: fused denominators, pre-scaled weights (i,f,o: log2e; g:
// 2log2e), cell in 2log2e-scaled domain. 7 trans + ~15 VALU per unit.
//   c' = [c*pi*pg + L2*(Eg-1)*pf] / (pf*pi*pg);  h = (Ec-1)/(po*(Ec+1))
//
// Register demand ~185 combined VGPR+AGPR -> 2 waves/SIMD (cap 256, no spill;
// 3 waves/SIMD (cap 168) would spill -> R2/R3 lesson).
__global__ __launch_bounds__(128, 2)
void lstm_fused(const float* __restrict__ x,
                const float* __restrict__ W_ih,
                const float* __restrict__ W_hh,
                const float* __restrict__ b_ih,
                const float* __restrict__ b_hh,
                const float* __restrict__ W_fc,
                const float* __restrict__ b_fc,
                float* __restrict__ out)
{
    __shared__ _Float16 sH[2][NSEQ * HS];     // h double-buffer: h[seq][unit]
    __shared__ float    sXT[SEQ_LEN * NSEQ];  // x tile, transposed [t][seq]

    const int tid  = threadIdx.x;
    const int wave = tid >> 6;
    const int lane = tid & 63;
    const int col  = lane & 15;
    const int quad = lane >> 4;
    const int seqBase = blockIdx.x * NSEQ;

    // ---- stage x transposed: sXT[t*32 + s] = x[(seqBase+s)*50 + t]
    for (int i = tid; i < SEQ_LEN * NSEQ; i += 128) {
        const int s = i & (NSEQ - 1);
        const int t = i >> 5;
        sXT[t * NSEQ + s] = x[(size_t)(seqBase + s) * SEQ_LEN + t];
    }
    // ---- zero both h buffers (h0 = 0)
    for (int i = tid; i < 2 * NSEQ * HS; i += 128)
        ((_Float16*)sH)[i] = (_Float16)0.0f;

    // ---- W_hh rows as resident fp16 A-fragments, pre-scaled.
    // A[m=col][k=quad*8+j] = W[unit][kf*32+quad*8+j]; shared by both n-tiles.
    h8 Aw[8][2];
    h8 Ax[8];
    #pragma unroll
    for (int gi = 0; gi < 4; ++gi) {
        const float scale = (gi == 2) ? LOG2E2 : LOG2E;
        #pragma unroll
        for (int d = 0; d < 2; ++d) {
            const int tt = gi * 2 + d;
            const int n  = (gi * 4 + 2 * wave + d) * 16 + col;
            h8 axf = {};
            if (quad == 0) {
                axf[0] = (_Float16)(W_ih[n] * scale);
                axf[1] = (_Float16)((b_ih[n] + b_hh[n]) * scale);
            }
            Ax[tt] = axf;
            #pragma unroll
            for (int kf = 0; kf < 2; ++kf) {
                const float* wp = W_hh + n * HID + kf * 32 + quad * 8;
                f4 lo = *(const f4*)wp;
                f4 hi = *(const f4*)(wp + 4);
                h8 b;
                b[0] = (_Float16)(lo[0] * scale); b[1] = (_Float16)(lo[1] * scale);
                b[2] = (_Float16)(lo[2] * scale); b[3] = (_Float16)(lo[3] * scale);
                b[4] = (_Float16)(hi[0] * scale); b[5] = (_Float16)(hi[1] * scale);
                b[6] = (_Float16)(hi[2] * scale); b[7] = (_Float16)(hi[3] * scale);
                Aw[tt][kf] = b;
            }
        }
    }

    const f4 z4 = {0.0f, 0.0f, 0.0f, 0.0f};

    // cell state c[d][n][r], 2log2e-scaled domain
    float c[2][2][4];
    #pragma unroll
    for (int d = 0; d < 2; ++d)
        #pragma unroll
        for (int n = 0; n < 2; ++n)
            #pragma unroll
            for (int r = 0; r < 4; ++r) c[d][n][r] = 0.0f;

    __syncthreads();

    for (int t = 0; t < SEQ_LEN; ++t) {
        const _Float16* hb = sH[t & 1];
        _Float16*       hw = sH[(t + 1) & 1];

        // B_x per n-tile = {x_t[seq], 1, 0...}
        h8 bx[2];
        #pragma unroll
        for (int n = 0; n < 2; ++n) {
            h8 b = {};
            b[0] = (_Float16)sXT[t * NSEQ + n * 16 + col];
            b[1] = (_Float16)1.0f;
            bx[n] = b;
        }

        // B = h^T fragments per n-tile: B[k=quad*8+j][seq=col]
        h8 Bh[2][2];
        #pragma unroll
        for (int n = 0; n < 2; ++n) {
            const _Float16* p = hb + (n * 16 + col) * HS + quad * 8;
            Bh[n][0] = *(const h8*)p;
            Bh[n][1] = *(const h8*)(p + 32);
        }

        // Two d-groups: 8 live accumulators (4 gates x 2 n-tiles)
        #pragma unroll
        for (int d = 0; d < 2; ++d) {
            f4 acc[4][2];
            #pragma unroll
            for (int gi = 0; gi < 4; ++gi) {
                const int tt = gi * 2 + d;
                #pragma unroll
                for (int n = 0; n < 2; ++n) {
                    f4 a = __builtin_amdgcn_mfma_f32_16x16x32_f16(Ax[tt], bx[n], z4, 0, 0, 0);
                    a = __builtin_amdgcn_mfma_f32_16x16x32_f16(Aw[tt][0], Bh[n][0], a, 0, 0, 0);
                    a = __builtin_amdgcn_mfma_f32_16x16x32_f16(Aw[tt][1], Bh[n][1], a, 0, 0, 0);
                    acc[gi][n] = a;
                }
            }
            // fused-denominator activations per n-tile
            #pragma unroll
            for (int n = 0; n < 2; ++n) {
                h4 hv;
                #pragma unroll
                for (int r = 0; r < 4; ++r) {
                    float Ei = EXP2(-acc[0][n][r]);
                    float Ef = EXP2(-acc[1][n][r]);
                    float Eg = EXP2( acc[2][n][r]);
                    float Eo = EXP2(-acc[3][n][r]);
                    float pi_ = 1.0f + Ei;
                    float pf_ = 1.0f + Ef;
                    float pg_ = 1.0f + Eg;
                    float po_ = 1.0f + Eo;
                    float t1  = pi_ * pg_;
                    float v   = fmaf(Eg, LOG2E2, -LOG2E2) * pf_;   // L2*(Eg-1)*pf
                    float num = fmaf(c[d][n][r], t1, v);
                    float rc  = RCP(pf_ * t1);
                    float cn  = fminf(num * rc, 126.0f);           // overflow guard
                    c[d][n][r] = cn;
                    float Ec  = EXP2(cn);
                    float rh  = RCP(po_ * (1.0f + Ec));
                    hv[r] = (_Float16)((Ec - 1.0f) * rh);
                }
                *(h4*)(hw + (n * 16 + col) * HS + 32 * wave + 16 * d + quad * 4) = hv;
            }
        }
        __syncthreads();
    }

    // ---- epilogue: final h in sH[0] (t=49 wrote buffer 0), h[seq][unit]
    if (tid < NSEQ * 3) {
        const int sl = tid / 3;
        const int nc = tid % 3;
        const _Float16* hp = sH[0] + sl * HS;
        float a = b_fc[nc];
        #pragma unroll
        for (int u = 0; u < HID; ++u)
            a = fmaf((float)hp[u], W_fc[nc * HID + u], a);
        out[(size_t)(seqBase + sl) * 3 + nc] = a;
    }
}

extern "C" void kernel_launch(void* const* d_in, const int* in_sizes, int n_in,
                              void* d_out, int out_size, void* d_ws, size_t ws_size,
                              hipStream_t stream) {
    const float* x    = (const float*)d_in[0];
    const float* W_ih = (const float*)d_in[1];
    const float* W_hh = (const float*)d_in[2];
    const float* b_ih = (const float*)d_in[3];
    const float* b_hh = (const float*)d_in[4];
    const float* W_fc = (const float*)d_in[5];
    const float* b_fc = (const float*)d_in[6];
    float* out = (float*)d_out;

    const int nSeq   = in_sizes[0] / SEQ_LEN;  // 512000
    const int blocks = nSeq / NSEQ;            // 16000

    hipLaunchKernelGGL(lstm_fused, dim3(blocks), dim3(128), 0, stream,
                       x, W_ih, W_hh, b_ih, b_hh, W_fc, b_fc, out);
}